// Round 7
// baseline (110.808 us; speedup 1.0000x reference)
//
#include <hip/hip_runtime.h>

// MXIntSoftmax — bit-exact integer port, round 7: 1 row / 128-thread block (2 waves),
// 2 barriers, wave-private output LUT, biased-index front-end.
//
// Semantics (verified absmax=0 in R1/R3..R6):
//   yb  = clip(trunc(clip(rne(x*2^(7-e)),-128,127)*46*2^(e-12) + 256), 0, 511)
//         (biased yq: trunc==floor for z>=0; z<0 clamps to 0 either way; e via exp-field math)
//   e8  = yb>>5 in [0,15] ; me4 = (rint(exp2((yb&31)/32+6))<<4)  [LUT, exact TAB match]
//   collapsed scan: partial += (me4 >> (E8-e8)) << E8, E8 = prefix max of e8 in row order
//   msum = total >> Estar8 in [1024,2^22); magic = floor(2^38/msum)+1 (f64, exact)
//   out  = finLUT[yb] fusing mout=floor(me*256/msum) (magic mul) + final mxint quant.

#define D_DIM 2048
#define TPB   128

// byte-wise max of two u32 whose bytes are <= 15
__device__ __forceinline__ unsigned bmax4(unsigned x, unsigned y) {
    const unsigned d     = (x | 0x80808080u) - y;
    const unsigned flags = d & 0x80808080u;
    const unsigned mask  = (flags - (flags >> 7)) | flags;
    return (x & mask) | (y & ~mask);
}

__global__ __launch_bounds__(TPB, 6) void mxint_softmax_kernel(const float* __restrict__ x,
                                                               float* __restrict__ out) {
    const int t    = threadIdx.x;
    const int lane = t & 63;
    const int wid  = t >> 6;                 // 0 = first half-row, 1 = second half-row

    __shared__ unsigned short     s_pk[512];      // me<<4 keyed by yb (static; fenced by B1)
    __shared__ float              s_fin[2][512];  // wave-private fused output LUT
    __shared__ int                s_rmax[2];
    __shared__ unsigned long long s_part[2];

    // ---- issue global loads first: wave covers 4 rounds x (64 lanes x float4) ----
    const size_t base = (size_t)blockIdx.x * D_DIM + wid * 1024 + lane * 4;
    float4 v[4];
#pragma unroll
    for (int i = 0; i < 4; ++i)
        v[i] = *(const float4*)(x + base + i * 256);

    // ---- static pk LUT: 4 entries/thread, overlaps load latency, fenced by B1 ----
#pragma unroll
    for (int q = 0; q < 4; ++q) {
        const int idx = t + TPB * q;                               // 0..511
        const float a = fmaf((float)(idx & 31), 0.03125f, 6.0f);
        const int  me = (int)rintf(__builtin_amdgcn_exp2f(a));     // exact TAB (17x margin)
        s_pk[idx] = (unsigned short)(me << 4);
    }

    // ---- front end: biased yb per element; per-round lane maxima packed as bytes ----
    int yb[16];
    unsigned pe = 0;
#pragma unroll
    for (int i = 0; i < 4; ++i) {
        const float xs4[4] = {v[i].x, v[i].y, v[i].z, v[i].w};
        int rmax = 0;
#pragma unroll
        for (int k = 0; k < 4; ++k) {
            const unsigned b  = __float_as_uint(xs4[k]) & 0x7fffffffu;
            const unsigned tb = b + 0x7fffffu;
            const unsigned tc = min(max(tb, 0x3B800000u), 0x43000000u); // clamp exp field
            const unsigned es = tc & 0xFF800000u;                       // ebc<<23
            const float    su  = __uint_as_float(0x82800000u - es);     // 2^(134-ebc)
            const float    fac = __uint_as_float(es + 0xFF380000u);     // 46*2^(ebc-134)
            const float    mi  = __builtin_amdgcn_fmed3f(rintf(xs4[k] * su), -128.0f, 127.0f);
            int y = (int)fmaf(mi, fac, 256.0f);       // trunc; ==floor for z>=0, clamps fix z<0
            y = min(511, max(0, y));                  // med3_i32
            yb[4 * i + k] = y;
            rmax = max(rmax, y);
        }
        pe |= (unsigned)(rmax >> 5) << (8 * i);       // biased e8 round-max byte
    }

    // ---- one SWAR wave scan (4 round-bytes at once) ----
    unsigned s = pe;
#pragma unroll
    for (int d = 1; d < 64; d <<= 1) {
        const unsigned o = __shfl_up(s, d, 64);
        if (lane >= d) s = bmax4(s, o);
    }
    unsigned ex = __shfl_up(s, 1, 64);
    if (lane == 0) ex = 0;
    const unsigned bc = __shfl(s, 63, 64);            // per-round wave totals
    const int wtot = max(max((int)(bc & 255u), (int)((bc >> 8) & 255u)),
                         max((int)((bc >> 16) & 255u), (int)(bc >> 24)));
    if (lane == 0) s_rmax[wid] = wtot;
    __syncthreads();                                  // B1: carry + pk LUT ready

    const int c0 = wid ? s_rmax[0] : 0;               // order carry for second half-row

    // ---- weighted sum (collapsed scan), u32 partial (16 terms <= 1.05e9) ----
    unsigned partial = 0;
    int crun = c0;
#pragma unroll
    for (int i = 0; i < 4; ++i) {
        const int sx = (int)((ex >> (8 * i)) & 255u);
        int a = max(crun, sx);
#pragma unroll
        for (int k = 0; k < 4; ++k) {
            const int y = yb[4 * i + k];
            const int h = y >> 5;                     // e8 in [0,15]
            a = max(a, h);                            // inclusive prefix max
            const unsigned me4 = s_pk[y];             // me<<4
            partial += (me4 >> (a - h)) << a;         // floor term << (E+8)
        }
        crun = max(crun, (int)((bc >> (8 * i)) & 255u));
    }

    // ---- butterfly reduce within wave (1 u32 step, then u64) ----
    const unsigned ps = partial + __shfl_xor(partial, 1, 64);    // pair < 2^31.1
    unsigned long long p64 = ps;
#pragma unroll
    for (int d = 2; d < 64; d <<= 1) p64 += __shfl_xor(p64, d, 64);
    if (lane == 0) s_part[wid] = p64;
    __syncthreads();                                  // B2: partials ready

    const unsigned long long tot = s_part[0] + s_part[1];
    const int      Estar8 = max(s_rmax[0], s_rmax[1]);
    const unsigned msum   = (unsigned)(tot >> Estar8);           // [1024, 2^22)
    const unsigned magic  = (unsigned)(274877906944.0 / (double)msum) + 1u; // floor(2^38/m)+1

    // ---- wave-private fused final LUT: 8 entries/lane, no barrier needed ----
    float* fin = s_fin[wid];
#pragma unroll
    for (int q = 0; q < 8; ++q) {
        const int      idx   = lane + 64 * q;                    // 0..511
        const unsigned me4   = s_pk[idx];
        const unsigned mout  = __umulhi((unsigned)me4 << 4, magic) >> 6;  // floor(me*256/msum)
        const int      eoutn = Estar8 - (idx >> 5);              // may be <0 for unused entries
        const int      bl    = 32 - __clz((int)(mout | 1u));
        const int      pw2   = ((mout & (mout - 1u)) == 0u) ? 1 : 0;
        const int      clog  = bl - pw2;                         // ceil(log2 mout)
        const int      sq    = min(7 - clog, 11 - eoutn);
        const int      rs    = 8 - sq;                           // >= 1
        const unsigned u     = mout << 8;
        const unsigned bse   = u >> rs;
        const unsigned frac  = u & ((1u << rs) - 1u);
        const unsigned hlf   = 1u << (rs - 1);
        unsigned m2 = bse + (((frac > hlf) || (frac == hlf && (bse & 1u))) ? 1u : 0u);
        m2 = min(m2, 127u);
        const int ef = max(clog - eoutn - 4, -8);
        fin[idx] = (float)m2 * __uint_as_float((unsigned)(ef + 120) << 23);
    }

    // ---- epilogue: one LDS read per element, coalesced float4 stores ----
    float* orow = out + base;
#pragma unroll
    for (int i = 0; i < 4; ++i) {
        float r4[4];
#pragma unroll
        for (int k = 0; k < 4; ++k)
            r4[k] = fin[yb[4 * i + k]];
        const float4 o4 = {r4[0], r4[1], r4[2], r4[3]};
        *(float4*)(orow + i * 256) = o4;
    }
}

extern "C" void kernel_launch(void* const* d_in, const int* in_sizes, int n_in,
                              void* d_out, int out_size, void* d_ws, size_t ws_size,
                              hipStream_t stream) {
    const float* x = (const float*)d_in[0];
    float*       o = (float*)d_out;
    const int rows = in_sizes[0] / D_DIM;      // 8192
    mxint_softmax_kernel<<<rows, TPB, 0, stream>>>(x, o);
}